// Round 18
// baseline (82.549 us; speedup 1.0000x reference)
//
#include <hip/hip_runtime.h>
#include <hip/hip_bf16.h>

// GNNRefiner: out = xyz + max_k( relu([x_i, x_j-x_i]·W1 + b1)·W2 + b2 )
// Factorization: e·W1 = x_i·(A-B) + x_j·B  with A=W1[0:387], B=W1[387:774].
// Pipeline (3 dispatches):
//   1) prep_assign: Xb rows + Wpt + x-sorted tiles (block-local slot allocation,
//      no global cursor/init) + tile bounds.
//   2) knn_gemm (fused, 1-in-6 interleave): knn waves (latency/SALU-bound) and
//      MFMA gemm waves co-resident per CU -> pipes overlap (time ~ max, not sum).
//   3) final (dim-parallel, validated r11).
// KNN: T = 16th-smallest of 64 disjoint-set lane minima (provable D16 upper bound);
// tile skipped iff gap^2 > T + 1e-3; candidates d<=T compacted (ballot-prefix) then
// exact radix top-16 by (d, idx) with singleton early-exit (provably exact).

#define N 8192
#define TD 384      // TOKEN_DIM
#define KNN 16
#define DX 387      // TD + 3
#define KP 416      // DX padded to multiple of 32
#define NF 768      // 2*TD output cols of fused GEMM
#define INFF __builtin_inff()

#define NB_X (N/2)          // 4096 prep blocks (2 points each)
#define NB_W NF             // 768 W-prep blocks
#define NB_A 32             // assign blocks
#define NGEMM 384           // gemm blocks (4 waves x 64x64 tile = 1536 tiles)

typedef __attribute__((ext_vector_type(8))) short short8;
typedef __attribute__((ext_vector_type(4))) float f32x4;
typedef __attribute__((ext_vector_type(2))) float f32x2;

// ---------------- packed fp32 helpers (bit-identical to scalar ops) ----------------

__device__ __forceinline__ f32x2 pk_mul(f32x2 a, f32x2 b) {
    f32x2 r; asm("v_pk_mul_f32 %0, %1, %2" : "=v"(r) : "v"(a), "v"(b)); return r;
}
__device__ __forceinline__ f32x2 pk_add(f32x2 a, f32x2 b) {
    f32x2 r; asm("v_pk_add_f32 %0, %1, %2" : "=v"(r) : "v"(a), "v"(b)); return r;
}
__device__ __forceinline__ f32x2 pk_sub(f32x2 a, f32x2 b) {
    f32x2 r; asm("v_pk_add_f32 %0, %1, %2 neg_lo:[0,1] neg_hi:[0,1]" : "=v"(r) : "v"(a), "v"(b)); return r;
}
__device__ __forceinline__ f32x2 pk_fma(f32x2 a, f32x2 b, f32x2 c) {
    f32x2 r; asm("v_pk_fma_f32 %0, %1, %2, %3" : "=v"(r) : "v"(a), "v"(b), "v"(c)); return r;
}

// d2 = (qw + sq_j) - 2*dot, dot = fma(qz,z, fma(qy,y, mul(qx,x)))  [bit-identical to ref]
__device__ __forceinline__ void dist4(f32x2 qx, f32x2 qy, f32x2 qz, f32x2 qw,
                                      f32x2 x01, f32x2 x23, f32x2 y01, f32x2 y23,
                                      f32x2 z01, f32x2 z23, f32x2 s01, f32x2 s23,
                                      f32x2& d01, f32x2& d23) {
    f32x2 dot01 = pk_fma(qz, z01, pk_fma(qy, y01, pk_mul(qx, x01)));
    f32x2 dot23 = pk_fma(qz, z23, pk_fma(qy, y23, pk_mul(qx, x23)));
    d01 = pk_sub(pk_add(qw, s01), pk_add(dot01, dot01));
    d23 = pk_sub(pk_add(qw, s23), pk_add(dot23, dot23));
}

// x-sort bin (identical expression everywhere -> deterministic)
__device__ __forceinline__ int xbin(float x) {
    int b = (int)((x + 4.0f) * 32.0f);
    return b < 0 ? 0 : (b > 255 ? 255 : b);
}

__device__ __forceinline__ float rdlane_f(float v, int src) {
    return __uint_as_float(__builtin_amdgcn_readlane(__float_as_uint(v), src));
}
__device__ __forceinline__ unsigned udmap(float x) {   // monotone float->uint map
    unsigned u = __float_as_uint(x);
    return ((int)u < 0) ? ~u : (u | 0x80000000u);
}

// ---------------- dispatch 1: prep + assign fused ----------------
// blocks [0,NB_X): Xb rows (2 points/block).  [NB_X,NB_X+NB_W): Wpt rows.
// [NB_X+NB_W, +NB_A): x-sort scatter with block-local allocation:
//   pos = exclusive_prefix(bin) + (#points of this bin in earlier blocks) + local rank.
// sorted tiles: per 256-slot tile: [x|y|z|sq|idx] x 256 (5120B)

__global__ void __launch_bounds__(256) prep_assign(const float* __restrict__ feat,
                                                   const float* __restrict__ xyz,
                                                   const float* __restrict__ W1,
                                                   __hip_bfloat16* __restrict__ Xb,
                                                   __hip_bfloat16* __restrict__ Wpt,
                                                   int* __restrict__ tlo,
                                                   int* __restrict__ thi,
                                                   float* __restrict__ stile) {
    const int b = blockIdx.x;
    const int t = threadIdx.x;
    if (b < NB_X) {
        const int half = t >> 7;
        const int tt = t & 127;
        const int p = b*2 + half;
        if (tt < 96) {  // vectorized feat copy: 96 x float4 -> 4 x bf16
            float4 f = reinterpret_cast<const float4*>(feat + (size_t)p*TD)[tt];
            __hip_bfloat16 h[4] = {__float2bfloat16(f.x), __float2bfloat16(f.y),
                                   __float2bfloat16(f.z), __float2bfloat16(f.w)};
            *reinterpret_cast<ulonglong1*>(Xb + p*KP + tt*4) = *reinterpret_cast<ulonglong1*>(h);
        } else {        // tail d = TD..KP-1 (32 dims across threads 96..127)
            int d = TD + (tt - 96);
            float v = (d < DX) ? xyz[p*3 + (d - TD)] : 0.f;
            Xb[p*KP + d] = __float2bfloat16(v);
        }
        return;
    }
    if (b < NB_X + NB_W) {
        const int f = b - NB_X;  // 0..767
        for (int k = t; k < KP; k += 256) {
            float v = 0.f;
            if (k < DX) {
                if (f < TD) v = W1[k*TD + f] - W1[(DX+k)*TD + f];
                else        v = W1[(DX+k)*TD + (f - TD)];
            }
            Wpt[f*KP + k] = __float2bfloat16(v);
        }
        return;
    }

    // ---- assign ----
    __shared__ int hcnt[256], pre[256], scan[256], cur[256];
    __shared__ int stlo[32], sthi[32];
    const int a = b - (NB_X + NB_W);   // 0..31
    hcnt[t] = 0; pre[t] = 0; cur[t] = 0;
    if (t < 32) { stlo[t] = 255; sthi[t] = 0; }
    __syncthreads();

    #pragma unroll
    for (int c = 0; c < 32; ++c) {
        int bin = xbin(xyz[(c*256 + t)*3]);
        atomicAdd(&hcnt[bin], 1);
        if (c < a) atomicAdd(&pre[bin], 1);   // points in earlier blocks (uniform cond)
    }
    __syncthreads();

    const int v = hcnt[t];
    scan[t] = v;
    __syncthreads();
    for (int off = 1; off < 256; off <<= 1) {
        int add = (t >= off) ? scan[t - off] : 0;
        __syncthreads();
        scan[t] += add;
        __syncthreads();
    }
    const int end = scan[t], start = end - v;   // inclusive / exclusive prefix
    if (a == 0 && v > 0) {                      // per-tile conservative bin range
        for (int x = start >> 8; x <= (end - 1) >> 8; ++x) {
            atomicMin(&stlo[x], t);
            atomicMax(&sthi[x], t);
        }
    }
    __syncthreads();
    scan[t] = start;                            // scan[] := exclusive prefix (base)
    __syncthreads();
    if (a == 0 && t < 32) { tlo[t] = stlo[t]; thi[t] = sthi[t]; }

    // scatter own point (slot order within bin nondeterministic; output-invariant)
    const int i = a*256 + t;
    float x = xyz[i*3+0], y = xyz[i*3+1], z = xyz[i*3+2];
    int bin = xbin(x);
    int pos = scan[bin] + pre[bin] + atomicAdd(&cur[bin], 1);
    float sq = __fadd_rn(__fadd_rn(__fmul_rn(x,x), __fmul_rn(y,y)), __fmul_rn(z,z));
    float* tp = stile + (pos >> 8) * 1280 + (pos & 255);
    tp[0] = x; tp[256] = y; tp[512] = z; tp[768] = sq;
    reinterpret_cast<int*>(tp)[1024] = i;
}

// ---------------- dispatch 2: knn + gemm fused ----------------
// u%6==5 && u/6<384 -> gemm block (4 waves, each a 64x64 tile); else knn block.

__global__ void __launch_bounds__(256) knn_gemm(const float* __restrict__ stile,
                                                const int* __restrict__ tlo,
                                                const int* __restrict__ thi,
                                                int* __restrict__ knn,
                                                const __hip_bfloat16* __restrict__ Xb,
                                                const __hip_bfloat16* __restrict__ Wpt,
                                                const float* __restrict__ b1,
                                                __hip_bfloat16* __restrict__ Ub,
                                                __hip_bfloat16* __restrict__ Vb) {
    __shared__ float    dcache[4][5][256];   // 20KB: pass-1 window distances (self = INF)
    __shared__ unsigned sbuf[4][128][2];     //  4KB: compacted (ud, idx)
    const int u = blockIdx.x;
    const int g = u / 6;
    const int r = u - g*6;
    const int lane = threadIdx.x & 63;
    const int wv   = threadIdx.x >> 6;

    if ((r == 5) && (g < NGEMM)) {
        // ---------------- gemm wave: tile tid = g*4 + wv ----------------
        const int tid = g*4 + wv;
        const int i0  = (tid & 127) * 64;
        const int f0  = (tid >> 7) * 64;
        const int lm  = lane & 15;
        const int lk  = (lane >> 4) * 8;

        f32x4 acc[4][4];
        #pragma unroll
        for (int rr = 0; rr < 4; ++rr)
            #pragma unroll
            for (int c = 0; c < 4; ++c)
                acc[rr][c] = (f32x4){0.f, 0.f, 0.f, 0.f};

        const __hip_bfloat16* xbase = Xb  + (size_t)(i0 + lm) * KP + lk;
        const __hip_bfloat16* wbase = Wpt + (size_t)(f0 + lm) * KP + lk;

        #pragma unroll
        for (int kk = 0; kk < 13; ++kk) {
            short8 aa[4], bb[4];
            #pragma unroll
            for (int rr = 0; rr < 4; ++rr)
                aa[rr] = *reinterpret_cast<const short8*>(xbase + (size_t)rr*16*KP + kk*32);
            #pragma unroll
            for (int c = 0; c < 4; ++c)
                bb[c] = *reinterpret_cast<const short8*>(wbase + (size_t)c*16*KP + kk*32);
            #pragma unroll
            for (int rr = 0; rr < 4; ++rr)
                #pragma unroll
                for (int c = 0; c < 4; ++c)
                    acc[rr][c] = __builtin_amdgcn_mfma_f32_16x16x32_bf16(aa[rr], bb[c], acc[rr][c], 0, 0, 0);
        }

        const bool isU = (f0 < TD);
        __hip_bfloat16* outb = isU ? (Ub + f0) : (Vb + (f0 - TD));
        float bias[4] = {0.f, 0.f, 0.f, 0.f};
        if (isU) {
            #pragma unroll
            for (int c = 0; c < 4; ++c) bias[c] = b1[f0 + c*16 + lm];
        }
        const int crow = (lane >> 4) * 4;
        #pragma unroll
        for (int rr = 0; rr < 4; ++rr)
            #pragma unroll
            for (int c = 0; c < 4; ++c)
                #pragma unroll
                for (int q = 0; q < 4; ++q)
                    outb[(size_t)(i0 + rr*16 + crow + q) * TD + c*16 + lm] =
                        __float2bfloat16(acc[rr][c][q] + bias[c]);
        return;
    }

    // ---------------- knn wave ----------------
    const int kb = u - ((g < NGEMM) ? g : NGEMM);   // knn block index 0..2047
    const int s  = kb * 4 + wv;                     // sorted slot = this wave's query
    const int tq   = s >> 8;
    const int sl   = (s & 255) >> 2;
    const int slot = s & 3;

    const float* qp = stile + tq*1280 + (s & 255);
    const float qx = qp[0], qy = qp[256], qz = qp[512], qw = qp[768];
    const int   qi = reinterpret_cast<const int*>(qp)[1024];
    const f32x2 qx2 = {qx,qx}, qy2 = {qy,qy}, qz2 = {qz,qz}, qw2 = {qw,qw};

    const float* lbase = stile + lane*4;
    const bool is_self_lane = (lane == sl);

    // ---- pass 1: compute + LDS-cache distances over the 5-tile x-window ----
    float mn = INFF;
    int lo = tq - 2; if (lo < 0) lo = 0; if (lo > 27) lo = 27;
    #pragma unroll
    for (int tt = 0; tt < 5; ++tt) {
        const int t = lo + tt;
        const float* tp = lbase + t*1280;
        float4 X = *(const float4*)(tp);
        float4 Y = *(const float4*)(tp + 256);
        float4 Z = *(const float4*)(tp + 512);
        float4 S = *(const float4*)(tp + 768);
        f32x2 x01 = {X.x,X.y}, x23 = {X.z,X.w};
        f32x2 y01 = {Y.x,Y.y}, y23 = {Y.z,Y.w};
        f32x2 z01 = {Z.x,Z.y}, z23 = {Z.z,Z.w};
        f32x2 s01 = {S.x,S.y}, s23 = {S.z,S.w};
        f32x2 d01, d23;
        dist4(qx2, qy2, qz2, qw2, x01, x23, y01, y23, z01, z23, s01, s23, d01, d23);
        if ((t == tq) && is_self_lane) {
            if      (slot == 0) d01[0] = INFF;
            else if (slot == 1) d01[1] = INFF;
            else if (slot == 2) d23[0] = INFF;
            else                d23[1] = INFF;
        }
        f32x4 dd = {d01[0], d01[1], d23[0], d23[1]};
        *reinterpret_cast<f32x4*>(&dcache[wv][tt][lane*4]) = dd;
        mn = fminf(mn, fminf(fminf(dd[0], dd[1]), fminf(dd[2], dd[3])));
    }

    // ---- T = exact 16th smallest of the 64 lane minima (radix, singleton early-exit) ----
    float T;
    {
        unsigned ub = udmap(mn);
        unsigned long long alive = ~0ull;
        int need = KNN;
        for (int b = 31; b >= 0; --b) {
            if (__popcll(alive) == 1) break;        // exact: singleton => answer found
            unsigned long long ones  = __ballot(((ub >> b) & 1u) != 0u);
            unsigned long long zeros = alive & ~ones;
            int cz = (int)__popcll(zeros);
            bool tz = (cz >= need);
            alive = tz ? zeros : (alive & ones);
            need  = tz ? need : (need - cz);
        }
        T = fmaxf(rdlane_f(mn, (int)__ffsll(alive) - 1), 0.f);
    }

    // ---- visit mask in registers (one coalesced tlo/thi read) ----
    unsigned mask;
    {
        const int ti = lane & 31;
        const int bl = tlo[ti], bh = thi[ti];
        const float xlo = (bl == 0)   ? -1e30f : (bl * 0.03125f - 4.0f);
        const float xhi = (bh == 255) ?  1e30f : ((bh + 1) * 0.03125f - 4.0f);
        float gap = fmaxf(0.f, fmaxf(xlo - qx, qx - xhi));
        bool gate = (gap * gap <= T + 1e-3f);
        mask = (unsigned)__ballot(gate && (lane < 32));
    }

    // ---- pass 2: compact candidates with d <= T (ballot-prefix) ----
    int cnt = 0;
    const unsigned long long ltm = (1ull << lane) - 1;

    auto push = [&](float dv, int idx) {
        bool pred = (dv <= T);
        unsigned long long bal = __ballot(pred);
        if (bal) {
            int posn = cnt + (int)__popcll(bal & ltm);
            if (pred && posn < 128) {
                sbuf[wv][posn][0] = udmap(dv);
                sbuf[wv][posn][1] = (unsigned)idx;
            }
            cnt += (int)__popcll(bal);
        }
    };

    // 2a: window tiles — cached distances + idx only
    #pragma unroll
    for (int tt = 0; tt < 5; ++tt) {
        const int t = lo + tt;
        if (!((mask >> t) & 1u)) continue;
        f32x4 dd = *reinterpret_cast<const f32x4*>(&dcache[wv][tt][lane*4]);
        int4 I = *(const int4*)(lbase + t*1280 + 1024);
        push(dd[0], I.x);
        push(dd[1], I.y);
        push(dd[2], I.z);
        push(dd[3], I.w);
    }
    // 2b: rare out-of-window survivors — recompute (t != tq)
    unsigned rest = mask & ~(0x1Fu << lo);
    while (rest) {
        const int t = (int)__ffs(rest) - 1;
        rest &= rest - 1;
        const float* tp = lbase + t*1280;
        float4 X = *(const float4*)(tp);
        float4 Y = *(const float4*)(tp + 256);
        float4 Z = *(const float4*)(tp + 512);
        float4 S = *(const float4*)(tp + 768);
        int4   I = *(const int4*)(tp + 1024);
        f32x2 x01 = {X.x,X.y}, x23 = {X.z,X.w};
        f32x2 y01 = {Y.x,Y.y}, y23 = {Y.z,Y.w};
        f32x2 z01 = {Z.x,Z.y}, z23 = {Z.z,Z.w};
        f32x2 s01 = {S.x,S.y}, s23 = {S.z,S.w};
        f32x2 d01, d23;
        dist4(qx2, qy2, qz2, qw2, x01, x23, y01, y23, z01, z23, s01, s23, d01, d23);
        float tmin = fminf(fminf(d01[0], d01[1]), fminf(d23[0], d23[1]));
        if (__ballot(tmin <= T)) {
            push(d01[0], I.x);
            push(d01[1], I.y);
            push(d23[0], I.z);
            push(d23[1], I.w);
        }
    }

    // ---- exact top-16 of compacted set: radix over ud (early-exit), idx tie-break ----
    asm volatile("s_waitcnt lgkmcnt(0)" ::: "memory");
    const int M = (cnt > 128) ? 128 : cnt;   // M >= 16 guaranteed

    if (M <= 64) {   // fast path (typical M ~ 20-40)
        unsigned ud1 = 0xFFFFFFFFu, id1 = 0xFFFFFFFFu;
        if (lane < M) { ud1 = sbuf[wv][lane][0]; id1 = sbuf[wv][lane][1]; }
        unsigned long long alive = __ballot(lane < M);
        int need = KNN;
        for (int b = 31; b >= 0; --b) {
            if (__popcll(alive) == 1) break;
            unsigned long long on = __ballot(((ud1 >> b) & 1u) != 0u);
            unsigned long long z  = alive & ~on;
            int cz = (int)__popcll(z);
            bool tz = (cz >= need);
            alive = tz ? z : (alive & on);
            need  = tz ? need : (need - cz);
        }
        unsigned v16 = (unsigned)__builtin_amdgcn_readlane((int)ud1, (int)__ffsll(alive) - 1);
        const bool all_ties = ((int)__popcll(alive) <= need);
        unsigned vidx = 0xFFFFFFFFu;
        if (!all_ties) {
            unsigned long long a = alive;
            int nd = need;
            for (int b = 31; b >= 0; --b) {
                if (__popcll(a) == 1) break;
                unsigned long long on = __ballot(((id1 >> b) & 1u) != 0u);
                unsigned long long z  = a & ~on;
                int cz = (int)__popcll(z);
                bool tz = (cz >= nd);
                a  = tz ? z : (a & on);
                nd = tz ? nd : (nd - cz);
            }
            vidx = (unsigned)__builtin_amdgcn_readlane((int)id1, (int)__ffsll(a) - 1);
        }
        bool sel = (lane < M) && ((ud1 < v16) || ((ud1 == v16) && (all_ties || (id1 <= vidx))));
        unsigned long long bs = __ballot(sel);
        if (sel) knn[qi*KNN + (int)__popcll(bs & ltm)] = (int)id1;
    } else {
        unsigned ud1 = 0xFFFFFFFFu, id1 = 0xFFFFFFFFu;
        unsigned ud2 = 0xFFFFFFFFu, id2 = 0xFFFFFFFFu;
        if (lane < M)      { ud1 = sbuf[wv][lane][0];      id1 = sbuf[wv][lane][1]; }
        if (lane + 64 < M) { ud2 = sbuf[wv][lane + 64][0]; id2 = sbuf[wv][lane + 64][1]; }

        unsigned long long alive1 = __ballot(lane < M);
        unsigned long long alive2 = __ballot(lane + 64 < M);
        int need = KNN;
        for (int b = 31; b >= 0; --b) {
            if ((int)__popcll(alive1) + (int)__popcll(alive2) == 1) break;
            unsigned long long on1 = __ballot(((ud1 >> b) & 1u) != 0u);
            unsigned long long on2 = __ballot(((ud2 >> b) & 1u) != 0u);
            unsigned long long z1 = alive1 & ~on1;
            unsigned long long z2 = alive2 & ~on2;
            int cz = (int)__popcll(z1) + (int)__popcll(z2);
            bool tz = (cz >= need);
            alive1 = tz ? z1 : (alive1 & on1);
            alive2 = tz ? z2 : (alive2 & on2);
            need   = tz ? need : (need - cz);
        }
        unsigned v16;
        if (alive1) v16 = (unsigned)__builtin_amdgcn_readlane((int)ud1, (int)__ffsll(alive1) - 1);
        else        v16 = (unsigned)__builtin_amdgcn_readlane((int)ud2, (int)__ffsll(alive2) - 1);

        const int nt = (int)__popcll(alive1) + (int)__popcll(alive2);
        const bool all_ties = (nt <= need);
        unsigned vidx = 0xFFFFFFFFu;
        if (!all_ties) {
            unsigned long long a1 = alive1, a2 = alive2;
            int nd = need;
            for (int b = 31; b >= 0; --b) {
                if ((int)__popcll(a1) + (int)__popcll(a2) == 1) break;
                unsigned long long on1 = __ballot(((id1 >> b) & 1u) != 0u);
                unsigned long long on2 = __ballot(((id2 >> b) & 1u) != 0u);
                unsigned long long z1 = a1 & ~on1;
                unsigned long long z2 = a2 & ~on2;
                int cz = (int)__popcll(z1) + (int)__popcll(z2);
                bool tz = (cz >= nd);
                a1 = tz ? z1 : (a1 & on1);
                a2 = tz ? z2 : (a2 & on2);
                nd = tz ? nd : (nd - cz);
            }
            if (a1) vidx = (unsigned)__builtin_amdgcn_readlane((int)id1, (int)__ffsll(a1) - 1);
            else    vidx = (unsigned)__builtin_amdgcn_readlane((int)id2, (int)__ffsll(a2) - 1);
        }

        bool sel1 = (lane < M)      && ((ud1 < v16) || ((ud1 == v16) && (all_ties || (id1 <= vidx))));
        bool sel2 = (lane + 64 < M) && ((ud2 < v16) || ((ud2 == v16) && (all_ties || (id2 <= vidx))));
        unsigned long long bs1 = __ballot(sel1);
        if (sel1) knn[qi*KNN + (int)__popcll(bs1 & ltm)] = (int)id1;
        const int c1 = (int)__popcll(bs1);
        unsigned long long bs2 = __ballot(sel2);
        if (sel2) knn[qi*KNN + c1 + (int)__popcll(bs2 & ltm)] = (int)id2;
    }
}

// ---------------- dispatch 3: final (dim-parallel, validated r11) ----------------

__device__ __forceinline__ float bflo(unsigned w) { return __uint_as_float(w << 16); }
__device__ __forceinline__ float bfhi(unsigned w) { return __uint_as_float(w & 0xFFFF0000u); }

template<int CTRL>
__device__ __forceinline__ float dppf(float v) {
    return __uint_as_float((unsigned)__builtin_amdgcn_update_dpp(
        0, (int)__float_as_uint(v), CTRL, 0xF, 0xF, true));
}

__global__ void __launch_bounds__(256) final_kernel(const __hip_bfloat16* __restrict__ Ub,
                                                    const __hip_bfloat16* __restrict__ Vb,
                                                    const int* __restrict__ knn,
                                                    const float* __restrict__ xyz,
                                                    const float* __restrict__ W2,
                                                    const float* __restrict__ b2,
                                                    float* __restrict__ out) {
    const int lane = threadIdx.x & 63;
    const int wv   = threadIdx.x >> 6;
    const int i    = blockIdx.x * 4 + wv;
    const int d0   = lane * 6;

    int jreg = knn[i*KNN + (lane & 15)];

    float u[6], w2l[6][3];
    {
        const unsigned* rowU = reinterpret_cast<const unsigned*>(Ub + (size_t)i * TD) + lane*3;
        unsigned a0 = rowU[0], a1 = rowU[1], a2 = rowU[2];
        u[0] = bflo(a0); u[1] = bfhi(a0);
        u[2] = bflo(a1); u[3] = bfhi(a1);
        u[4] = bflo(a2); u[5] = bfhi(a2);
    }
    #pragma unroll
    for (int t = 0; t < 6; ++t)
        #pragma unroll
        for (int c = 0; c < 3; ++c) w2l[t][c] = W2[(d0 + t)*3 + c];

    const unsigned* vbase = reinterpret_cast<const unsigned*>(Vb);
    const int voff = lane * 3;

    float pk0[16], pk1[16], pk2[16];
    unsigned va[2][4][3];

    #pragma unroll
    for (int t = 0; t < 4; ++t) {
        int j = __builtin_amdgcn_readlane(jreg, t);
        const unsigned* rv = vbase + (size_t)j * 192 + voff;
        va[0][t][0] = rv[0]; va[0][t][1] = rv[1]; va[0][t][2] = rv[2];
    }
    __builtin_amdgcn_sched_barrier(0);

    #pragma unroll
    for (int b = 0; b < 4; ++b) {
        if (b < 3) {
            #pragma unroll
            for (int t = 0; t < 4; ++t) {
                int j = __builtin_amdgcn_readlane(jreg, (b+1)*4 + t);
                const unsigned* rv = vbase + (size_t)j * 192 + voff;
                va[(b+1)&1][t][0] = rv[0];
                va[(b+1)&1][t][1] = rv[1];
                va[(b+1)&1][t][2] = rv[2];
            }
            __builtin_amdgcn_sched_barrier(0);
        }
        #pragma unroll
        for (int t = 0; t < 4; ++t) {
            const int kk = b*4 + t;
            unsigned a0 = va[b&1][t][0], a1 = va[b&1][t][1], a2 = va[b&1][t][2];
            float v0 = bflo(a0), v1 = bfhi(a0);
            float v2 = bflo(a1), v3 = bfhi(a1);
            float v4 = bflo(a2), v5 = bfhi(a2);
            float h0 = fmaxf(u[0] + v0, 0.f), h1 = fmaxf(u[1] + v1, 0.f);
            float h2 = fmaxf(u[2] + v2, 0.f), h3 = fmaxf(u[3] + v3, 0.f);
            float h4 = fmaxf(u[4] + v4, 0.f), h5 = fmaxf(u[5] + v5, 0.f);
            float s0 = 0.f, s1 = 0.f, s2 = 0.f;
            s0 = fmaf(h0, w2l[0][0], s0); s1 = fmaf(h0, w2l[0][1], s1); s2 = fmaf(h0, w2l[0][2], s2);
            s0 = fmaf(h1, w2l[1][0], s0); s1 = fmaf(h1, w2l[1][1], s1); s2 = fmaf(h1, w2l[1][2], s2);
            s0 = fmaf(h2, w2l[2][0], s0); s1 = fmaf(h2, w2l[2][1], s1); s2 = fmaf(h2, w2l[2][2], s2);
            s0 = fmaf(h3, w2l[3][0], s0); s1 = fmaf(h3, w2l[3][1], s1); s2 = fmaf(h3, w2l[3][2], s2);
            s0 = fmaf(h4, w2l[4][0], s0); s1 = fmaf(h4, w2l[4][1], s1); s2 = fmaf(h4, w2l[4][2], s2);
            s0 = fmaf(h5, w2l[5][0], s0); s1 = fmaf(h5, w2l[5][1], s1); s2 = fmaf(h5, w2l[5][2], s2);
            pk0[kk] = s0; pk1[kk] = s1; pk2[kk] = s2;
        }
    }

    #pragma unroll
    for (int kk = 0; kk < 16; ++kk) {
        float r0 = pk0[kk], r1 = pk1[kk], r2 = pk2[kk];
        r0 += dppf<0x121>(r0); r1 += dppf<0x121>(r1); r2 += dppf<0x121>(r2);
        r0 += dppf<0x122>(r0); r1 += dppf<0x122>(r1); r2 += dppf<0x122>(r2);
        r0 += dppf<0x124>(r0); r1 += dppf<0x124>(r1); r2 += dppf<0x124>(r2);
        r0 += dppf<0x128>(r0); r1 += dppf<0x128>(r1); r2 += dppf<0x128>(r2);
        r0 += __shfl_xor(r0, 16); r1 += __shfl_xor(r1, 16); r2 += __shfl_xor(r2, 16);
        r0 += __shfl_xor(r0, 32); r1 += __shfl_xor(r1, 32); r2 += __shfl_xor(r2, 32);
        pk0[kk] = r0; pk1[kk] = r1; pk2[kk] = r2;
    }
    float mx0 = pk0[0], mx1 = pk1[0], mx2 = pk2[0];
    #pragma unroll
    for (int kk = 1; kk < 16; ++kk) {
        mx0 = fmaxf(mx0, pk0[kk]);
        mx1 = fmaxf(mx1, pk1[kk]);
        mx2 = fmaxf(mx2, pk2[kk]);
    }

    if (lane == 0) {
        out[i*3+0] = xyz[i*3+0] + mx0 + b2[0];
        out[i*3+1] = xyz[i*3+1] + mx1 + b2[1];
        out[i*3+2] = xyz[i*3+2] + mx2 + b2[2];
    }
}

// ---------------- launch ----------------

extern "C" void kernel_launch(void* const* d_in, const int* in_sizes, int n_in,
                              void* d_out, int out_size, void* d_ws, size_t ws_size,
                              hipStream_t stream) {
    const float* xyz  = (const float*)d_in[0];
    const float* feat = (const float*)d_in[1];
    const float* W1   = (const float*)d_in[2];
    const float* b1   = (const float*)d_in[3];
    const float* W2   = (const float*)d_in[4];
    const float* b2   = (const float*)d_in[5];
    float* out = (float*)d_out;

    char* ws = (char*)d_ws;
    int*            knn   = (int*)(ws + 0);                   //   524288 B
    float*          stile = (float*)(ws + 524288);            //   163840 B
    __hip_bfloat16* Xb    = (__hip_bfloat16*)(ws + 688128);   //  6815744 B
    __hip_bfloat16* Wpt   = (__hip_bfloat16*)(ws + 7503872);  //   638976 B
    __hip_bfloat16* Ub    = (__hip_bfloat16*)(ws + 8142848);  //  6291456 B
    __hip_bfloat16* Vb    = (__hip_bfloat16*)(ws + 14434304); //  6291456 B
    int*            thi   = (int*)(ws + 20725760);            //      128 B
    int*            tlo   = (int*)(ws + 20725888);            //      128 B -> end 20726016

    prep_assign <<<dim3(NB_X + NB_W + NB_A),       dim3(256), 0, stream>>>(
        feat, xyz, W1, Xb, Wpt, tlo, thi, stile);
    knn_gemm    <<<dim3(N/4 + NGEMM),              dim3(256), 0, stream>>>(
        stile, tlo, thi, knn, Xb, Wpt, b1, Ub, Vb);
    final_kernel<<<dim3(N/4),                      dim3(256), 0, stream>>>(
        Ub, Vb, knn, xyz, W2, b2, out);
}

// Round 19
// 75.632 us; speedup vs baseline: 1.0915x; 1.0915x over previous
//
#include <hip/hip_runtime.h>
#include <hip/hip_bf16.h>

// GNNRefiner: out = xyz + max_k( relu([x_i, x_j-x_i]·W1 + b1)·W2 + b2 )
// Factorization: e·W1 = x_i·(A-B) + x_j·B  with A=W1[0:387], B=W1[387:774].
// Pipeline (3 dispatches):
//   1) prep_assign: Xb rows + Wpt + x-sorted tiles (block-local slot alloc) + bounds.
//   2) knn_gemm fused at ONE-WAVE (64-thread) block granularity: 8192 knn blocks
//      (6KB LDS -> ~26 resident/CU, no intra-block straggler coupling) + 1536 gemm
//      tile blocks interleaved 1-in-6 -> knn (SALU/latency) and gemm (MFMA) overlap.
//   3) final (dim-parallel, validated r11).
// KNN: T = 16th-smallest of 64 disjoint-set lane minima (provable D16 upper bound);
// tile skipped iff gap^2 > T + 1e-3; candidates d<=T compacted (ballot-prefix) then
// exact radix top-16 by (d, idx) with singleton early-exit (provably exact).

#define N 8192
#define TD 384      // TOKEN_DIM
#define KNN 16
#define DX 387      // TD + 3
#define KP 416      // DX padded to multiple of 32
#define NF 768      // 2*TD output cols of fused GEMM
#define INFF __builtin_inff()

#define NB_X (N/2)          // 4096 prep blocks (2 points each)
#define NB_W NF             // 768 W-prep blocks
#define NB_A 32             // assign blocks
#define NGEMM_T 1536        // gemm tile blocks (1 wave = one 64x64 tile)

typedef __attribute__((ext_vector_type(8))) short short8;
typedef __attribute__((ext_vector_type(4))) float f32x4;
typedef __attribute__((ext_vector_type(2))) float f32x2;

// ---------------- packed fp32 helpers (bit-identical to scalar ops) ----------------

__device__ __forceinline__ f32x2 pk_mul(f32x2 a, f32x2 b) {
    f32x2 r; asm("v_pk_mul_f32 %0, %1, %2" : "=v"(r) : "v"(a), "v"(b)); return r;
}
__device__ __forceinline__ f32x2 pk_add(f32x2 a, f32x2 b) {
    f32x2 r; asm("v_pk_add_f32 %0, %1, %2" : "=v"(r) : "v"(a), "v"(b)); return r;
}
__device__ __forceinline__ f32x2 pk_sub(f32x2 a, f32x2 b) {
    f32x2 r; asm("v_pk_add_f32 %0, %1, %2 neg_lo:[0,1] neg_hi:[0,1]" : "=v"(r) : "v"(a), "v"(b)); return r;
}
__device__ __forceinline__ f32x2 pk_fma(f32x2 a, f32x2 b, f32x2 c) {
    f32x2 r; asm("v_pk_fma_f32 %0, %1, %2, %3" : "=v"(r) : "v"(a), "v"(b), "v"(c)); return r;
}

// d2 = (qw + sq_j) - 2*dot, dot = fma(qz,z, fma(qy,y, mul(qx,x)))  [bit-identical to ref]
__device__ __forceinline__ void dist4(f32x2 qx, f32x2 qy, f32x2 qz, f32x2 qw,
                                      f32x2 x01, f32x2 x23, f32x2 y01, f32x2 y23,
                                      f32x2 z01, f32x2 z23, f32x2 s01, f32x2 s23,
                                      f32x2& d01, f32x2& d23) {
    f32x2 dot01 = pk_fma(qz, z01, pk_fma(qy, y01, pk_mul(qx, x01)));
    f32x2 dot23 = pk_fma(qz, z23, pk_fma(qy, y23, pk_mul(qx, x23)));
    d01 = pk_sub(pk_add(qw, s01), pk_add(dot01, dot01));
    d23 = pk_sub(pk_add(qw, s23), pk_add(dot23, dot23));
}

// x-sort bin (identical expression everywhere -> deterministic)
__device__ __forceinline__ int xbin(float x) {
    int b = (int)((x + 4.0f) * 32.0f);
    return b < 0 ? 0 : (b > 255 ? 255 : b);
}

__device__ __forceinline__ float rdlane_f(float v, int src) {
    return __uint_as_float(__builtin_amdgcn_readlane(__float_as_uint(v), src));
}
__device__ __forceinline__ unsigned udmap(float x) {   // monotone float->uint map
    unsigned u = __float_as_uint(x);
    return ((int)u < 0) ? ~u : (u | 0x80000000u);
}

// ---------------- dispatch 1: prep + assign fused ----------------
// blocks [0,NB_X): Xb rows (2 points/block).  [NB_X,NB_X+NB_W): Wpt rows.
// [NB_X+NB_W, +NB_A): x-sort scatter with block-local allocation.
// sorted tiles: per 256-slot tile: [x|y|z|sq|idx] x 256 (5120B)

__global__ void __launch_bounds__(256) prep_assign(const float* __restrict__ feat,
                                                   const float* __restrict__ xyz,
                                                   const float* __restrict__ W1,
                                                   __hip_bfloat16* __restrict__ Xb,
                                                   __hip_bfloat16* __restrict__ Wpt,
                                                   int* __restrict__ tlo,
                                                   int* __restrict__ thi,
                                                   float* __restrict__ stile) {
    const int b = blockIdx.x;
    const int t = threadIdx.x;
    if (b < NB_X) {
        const int half = t >> 7;
        const int tt = t & 127;
        const int p = b*2 + half;
        if (tt < 96) {  // vectorized feat copy: 96 x float4 -> 4 x bf16
            float4 f = reinterpret_cast<const float4*>(feat + (size_t)p*TD)[tt];
            __hip_bfloat16 h[4] = {__float2bfloat16(f.x), __float2bfloat16(f.y),
                                   __float2bfloat16(f.z), __float2bfloat16(f.w)};
            *reinterpret_cast<ulonglong1*>(Xb + p*KP + tt*4) = *reinterpret_cast<ulonglong1*>(h);
        } else {        // tail d = TD..KP-1 (32 dims across threads 96..127)
            int d = TD + (tt - 96);
            float v = (d < DX) ? xyz[p*3 + (d - TD)] : 0.f;
            Xb[p*KP + d] = __float2bfloat16(v);
        }
        return;
    }
    if (b < NB_X + NB_W) {
        const int f = b - NB_X;  // 0..767
        for (int k = t; k < KP; k += 256) {
            float v = 0.f;
            if (k < DX) {
                if (f < TD) v = W1[k*TD + f] - W1[(DX+k)*TD + f];
                else        v = W1[(DX+k)*TD + (f - TD)];
            }
            Wpt[f*KP + k] = __float2bfloat16(v);
        }
        return;
    }

    // ---- assign ----
    __shared__ int hcnt[256], pre[256], scan[256], cur[256];
    __shared__ int stlo[32], sthi[32];
    const int a = b - (NB_X + NB_W);   // 0..31
    hcnt[t] = 0; pre[t] = 0; cur[t] = 0;
    if (t < 32) { stlo[t] = 255; sthi[t] = 0; }
    __syncthreads();

    #pragma unroll
    for (int c = 0; c < 32; ++c) {
        int bin = xbin(xyz[(c*256 + t)*3]);
        atomicAdd(&hcnt[bin], 1);
        if (c < a) atomicAdd(&pre[bin], 1);   // points in earlier blocks (uniform cond)
    }
    __syncthreads();

    const int v = hcnt[t];
    scan[t] = v;
    __syncthreads();
    for (int off = 1; off < 256; off <<= 1) {
        int add = (t >= off) ? scan[t - off] : 0;
        __syncthreads();
        scan[t] += add;
        __syncthreads();
    }
    const int end = scan[t], start = end - v;   // inclusive / exclusive prefix
    if (a == 0 && v > 0) {                      // per-tile conservative bin range
        for (int x = start >> 8; x <= (end - 1) >> 8; ++x) {
            atomicMin(&stlo[x], t);
            atomicMax(&sthi[x], t);
        }
    }
    __syncthreads();
    scan[t] = start;                            // scan[] := exclusive prefix (base)
    __syncthreads();
    if (a == 0 && t < 32) { tlo[t] = stlo[t]; thi[t] = sthi[t]; }

    // scatter own point (slot order within bin nondeterministic; output-invariant)
    const int i = a*256 + t;
    float x = xyz[i*3+0], y = xyz[i*3+1], z = xyz[i*3+2];
    int bin = xbin(x);
    int pos = scan[bin] + pre[bin] + atomicAdd(&cur[bin], 1);
    float sq = __fadd_rn(__fadd_rn(__fmul_rn(x,x), __fmul_rn(y,y)), __fmul_rn(z,z));
    float* tp = stile + (pos >> 8) * 1280 + (pos & 255);
    tp[0] = x; tp[256] = y; tp[512] = z; tp[768] = sq;
    reinterpret_cast<int*>(tp)[1024] = i;
}

// ---------------- dispatch 2: knn + gemm fused, ONE WAVE per block ----------------
// u%6==5 && u/6<NGEMM_T -> gemm tile block; else knn query block.
// knn block index kb = u - min(u/6, NGEMM_T)  (bijective onto 0..8191).

__global__ void __launch_bounds__(64) knn_gemm(const float* __restrict__ stile,
                                               const int* __restrict__ tlo,
                                               const int* __restrict__ thi,
                                               int* __restrict__ knn,
                                               const __hip_bfloat16* __restrict__ Xb,
                                               const __hip_bfloat16* __restrict__ Wpt,
                                               const float* __restrict__ b1,
                                               __hip_bfloat16* __restrict__ Ub,
                                               __hip_bfloat16* __restrict__ Vb) {
    __shared__ float    dcache[5][256];   // 5KB: pass-1 window distances (self = INF)
    __shared__ unsigned sbuf[128][2];     // 1KB: compacted (ud, idx)
    const int u = blockIdx.x;
    const int g = u / 6;
    const int r = u - g*6;
    const int lane = threadIdx.x;

    if ((r == 5) && (g < NGEMM_T)) {
        // ---------------- gemm block: one 64x64 tile ----------------
        const int i0  = (g & 127) * 64;
        const int f0  = (g >> 7) * 64;
        const int lm  = lane & 15;
        const int lk  = (lane >> 4) * 8;

        f32x4 acc[4][4];
        #pragma unroll
        for (int rr = 0; rr < 4; ++rr)
            #pragma unroll
            for (int c = 0; c < 4; ++c)
                acc[rr][c] = (f32x4){0.f, 0.f, 0.f, 0.f};

        const __hip_bfloat16* xbase = Xb  + (size_t)(i0 + lm) * KP + lk;
        const __hip_bfloat16* wbase = Wpt + (size_t)(f0 + lm) * KP + lk;

        #pragma unroll
        for (int kk = 0; kk < 13; ++kk) {
            short8 aa[4], bb[4];
            #pragma unroll
            for (int rr = 0; rr < 4; ++rr)
                aa[rr] = *reinterpret_cast<const short8*>(xbase + (size_t)rr*16*KP + kk*32);
            #pragma unroll
            for (int c = 0; c < 4; ++c)
                bb[c] = *reinterpret_cast<const short8*>(wbase + (size_t)c*16*KP + kk*32);
            #pragma unroll
            for (int rr = 0; rr < 4; ++rr)
                #pragma unroll
                for (int c = 0; c < 4; ++c)
                    acc[rr][c] = __builtin_amdgcn_mfma_f32_16x16x32_bf16(aa[rr], bb[c], acc[rr][c], 0, 0, 0);
        }

        const bool isU = (f0 < TD);
        __hip_bfloat16* outb = isU ? (Ub + f0) : (Vb + (f0 - TD));
        float bias[4] = {0.f, 0.f, 0.f, 0.f};
        if (isU) {
            #pragma unroll
            for (int c = 0; c < 4; ++c) bias[c] = b1[f0 + c*16 + lm];
        }
        const int crow = (lane >> 4) * 4;
        #pragma unroll
        for (int rr = 0; rr < 4; ++rr)
            #pragma unroll
            for (int c = 0; c < 4; ++c)
                #pragma unroll
                for (int q = 0; q < 4; ++q)
                    outb[(size_t)(i0 + rr*16 + crow + q) * TD + c*16 + lm] =
                        __float2bfloat16(acc[rr][c][q] + bias[c]);
        return;
    }

    // ---------------- knn block: one query ----------------
    const int s  = u - ((g < NGEMM_T) ? g : NGEMM_T);   // sorted slot 0..8191
    const int tq   = s >> 8;
    const int sl   = (s & 255) >> 2;
    const int slot = s & 3;

    const float* qp = stile + tq*1280 + (s & 255);
    const float qx = qp[0], qy = qp[256], qz = qp[512], qw = qp[768];
    const int   qi = reinterpret_cast<const int*>(qp)[1024];
    const f32x2 qx2 = {qx,qx}, qy2 = {qy,qy}, qz2 = {qz,qz}, qw2 = {qw,qw};

    const float* lbase = stile + lane*4;
    const bool is_self_lane = (lane == sl);

    // ---- pass 1: compute + LDS-cache distances over the 5-tile x-window ----
    float mn = INFF;
    int lo = tq - 2; if (lo < 0) lo = 0; if (lo > 27) lo = 27;
    #pragma unroll
    for (int tt = 0; tt < 5; ++tt) {
        const int t = lo + tt;
        const float* tp = lbase + t*1280;
        float4 X = *(const float4*)(tp);
        float4 Y = *(const float4*)(tp + 256);
        float4 Z = *(const float4*)(tp + 512);
        float4 S = *(const float4*)(tp + 768);
        f32x2 x01 = {X.x,X.y}, x23 = {X.z,X.w};
        f32x2 y01 = {Y.x,Y.y}, y23 = {Y.z,Y.w};
        f32x2 z01 = {Z.x,Z.y}, z23 = {Z.z,Z.w};
        f32x2 s01 = {S.x,S.y}, s23 = {S.z,S.w};
        f32x2 d01, d23;
        dist4(qx2, qy2, qz2, qw2, x01, x23, y01, y23, z01, z23, s01, s23, d01, d23);
        if ((t == tq) && is_self_lane) {
            if      (slot == 0) d01[0] = INFF;
            else if (slot == 1) d01[1] = INFF;
            else if (slot == 2) d23[0] = INFF;
            else                d23[1] = INFF;
        }
        f32x4 dd = {d01[0], d01[1], d23[0], d23[1]};
        *reinterpret_cast<f32x4*>(&dcache[tt][lane*4]) = dd;
        mn = fminf(mn, fminf(fminf(dd[0], dd[1]), fminf(dd[2], dd[3])));
    }

    // ---- T = exact 16th smallest of the 64 lane minima (radix, singleton early-exit) ----
    float T;
    {
        unsigned ub = udmap(mn);
        unsigned long long alive = ~0ull;
        int need = KNN;
        for (int b = 31; b >= 0; --b) {
            if (__popcll(alive) == 1) break;        // exact: singleton => answer found
            unsigned long long ones  = __ballot(((ub >> b) & 1u) != 0u);
            unsigned long long zeros = alive & ~ones;
            int cz = (int)__popcll(zeros);
            bool tz = (cz >= need);
            alive = tz ? zeros : (alive & ones);
            need  = tz ? need : (need - cz);
        }
        T = fmaxf(rdlane_f(mn, (int)__ffsll(alive) - 1), 0.f);
    }

    // ---- visit mask in registers (one coalesced tlo/thi read) ----
    unsigned mask;
    {
        const int ti = lane & 31;
        const int bl = tlo[ti], bh = thi[ti];
        const float xlo = (bl == 0)   ? -1e30f : (bl * 0.03125f - 4.0f);
        const float xhi = (bh == 255) ?  1e30f : ((bh + 1) * 0.03125f - 4.0f);
        float gap = fmaxf(0.f, fmaxf(xlo - qx, qx - xhi));
        bool gate = (gap * gap <= T + 1e-3f);
        mask = (unsigned)__ballot(gate && (lane < 32));
    }

    // ---- pass 2: compact candidates with d <= T (ballot-prefix) ----
    int cnt = 0;
    const unsigned long long ltm = (1ull << lane) - 1;

    auto push = [&](float dv, int idx) {
        bool pred = (dv <= T);
        unsigned long long bal = __ballot(pred);
        if (bal) {
            int posn = cnt + (int)__popcll(bal & ltm);
            if (pred && posn < 128) {
                sbuf[posn][0] = udmap(dv);
                sbuf[posn][1] = (unsigned)idx;
            }
            cnt += (int)__popcll(bal);
        }
    };

    // 2a: window tiles — cached distances + idx only
    #pragma unroll
    for (int tt = 0; tt < 5; ++tt) {
        const int t = lo + tt;
        if (!((mask >> t) & 1u)) continue;
        f32x4 dd = *reinterpret_cast<const f32x4*>(&dcache[tt][lane*4]);
        int4 I = *(const int4*)(lbase + t*1280 + 1024);
        push(dd[0], I.x);
        push(dd[1], I.y);
        push(dd[2], I.z);
        push(dd[3], I.w);
    }
    // 2b: rare out-of-window survivors — recompute (t != tq)
    unsigned rest = mask & ~(0x1Fu << lo);
    while (rest) {
        const int t = (int)__ffs(rest) - 1;
        rest &= rest - 1;
        const float* tp = lbase + t*1280;
        float4 X = *(const float4*)(tp);
        float4 Y = *(const float4*)(tp + 256);
        float4 Z = *(const float4*)(tp + 512);
        float4 S = *(const float4*)(tp + 768);
        int4   I = *(const int4*)(tp + 1024);
        f32x2 x01 = {X.x,X.y}, x23 = {X.z,X.w};
        f32x2 y01 = {Y.x,Y.y}, y23 = {Y.z,Y.w};
        f32x2 z01 = {Z.x,Z.y}, z23 = {Z.z,Z.w};
        f32x2 s01 = {S.x,S.y}, s23 = {S.z,S.w};
        f32x2 d01, d23;
        dist4(qx2, qy2, qz2, qw2, x01, x23, y01, y23, z01, z23, s01, s23, d01, d23);
        float tmin = fminf(fminf(d01[0], d01[1]), fminf(d23[0], d23[1]));
        if (__ballot(tmin <= T)) {
            push(d01[0], I.x);
            push(d01[1], I.y);
            push(d23[0], I.z);
            push(d23[1], I.w);
        }
    }

    // ---- exact top-16 of compacted set: radix over ud (early-exit), idx tie-break ----
    asm volatile("s_waitcnt lgkmcnt(0)" ::: "memory");
    const int M = (cnt > 128) ? 128 : cnt;   // M >= 16 guaranteed

    if (M <= 64) {   // fast path (typical M ~ 20-40)
        unsigned ud1 = 0xFFFFFFFFu, id1 = 0xFFFFFFFFu;
        if (lane < M) { ud1 = sbuf[lane][0]; id1 = sbuf[lane][1]; }
        unsigned long long alive = __ballot(lane < M);
        int need = KNN;
        for (int b = 31; b >= 0; --b) {
            if (__popcll(alive) == 1) break;
            unsigned long long on = __ballot(((ud1 >> b) & 1u) != 0u);
            unsigned long long z  = alive & ~on;
            int cz = (int)__popcll(z);
            bool tz = (cz >= need);
            alive = tz ? z : (alive & on);
            need  = tz ? need : (need - cz);
        }
        unsigned v16 = (unsigned)__builtin_amdgcn_readlane((int)ud1, (int)__ffsll(alive) - 1);
        const bool all_ties = ((int)__popcll(alive) <= need);
        unsigned vidx = 0xFFFFFFFFu;
        if (!all_ties) {
            unsigned long long a = alive;
            int nd = need;
            for (int b = 31; b >= 0; --b) {
                if (__popcll(a) == 1) break;
                unsigned long long on = __ballot(((id1 >> b) & 1u) != 0u);
                unsigned long long z  = a & ~on;
                int cz = (int)__popcll(z);
                bool tz = (cz >= nd);
                a  = tz ? z : (a & on);
                nd = tz ? nd : (nd - cz);
            }
            vidx = (unsigned)__builtin_amdgcn_readlane((int)id1, (int)__ffsll(a) - 1);
        }
        bool sel = (lane < M) && ((ud1 < v16) || ((ud1 == v16) && (all_ties || (id1 <= vidx))));
        unsigned long long bs = __ballot(sel);
        if (sel) knn[qi*KNN + (int)__popcll(bs & ltm)] = (int)id1;
    } else {
        unsigned ud1 = 0xFFFFFFFFu, id1 = 0xFFFFFFFFu;
        unsigned ud2 = 0xFFFFFFFFu, id2 = 0xFFFFFFFFu;
        if (lane < M)      { ud1 = sbuf[lane][0];      id1 = sbuf[lane][1]; }
        if (lane + 64 < M) { ud2 = sbuf[lane + 64][0]; id2 = sbuf[lane + 64][1]; }

        unsigned long long alive1 = __ballot(lane < M);
        unsigned long long alive2 = __ballot(lane + 64 < M);
        int need = KNN;
        for (int b = 31; b >= 0; --b) {
            if ((int)__popcll(alive1) + (int)__popcll(alive2) == 1) break;
            unsigned long long on1 = __ballot(((ud1 >> b) & 1u) != 0u);
            unsigned long long on2 = __ballot(((ud2 >> b) & 1u) != 0u);
            unsigned long long z1 = alive1 & ~on1;
            unsigned long long z2 = alive2 & ~on2;
            int cz = (int)__popcll(z1) + (int)__popcll(z2);
            bool tz = (cz >= need);
            alive1 = tz ? z1 : (alive1 & on1);
            alive2 = tz ? z2 : (alive2 & on2);
            need   = tz ? need : (need - cz);
        }
        unsigned v16;
        if (alive1) v16 = (unsigned)__builtin_amdgcn_readlane((int)ud1, (int)__ffsll(alive1) - 1);
        else        v16 = (unsigned)__builtin_amdgcn_readlane((int)ud2, (int)__ffsll(alive2) - 1);

        const int nt = (int)__popcll(alive1) + (int)__popcll(alive2);
        const bool all_ties = (nt <= need);
        unsigned vidx = 0xFFFFFFFFu;
        if (!all_ties) {
            unsigned long long a1 = alive1, a2 = alive2;
            int nd = need;
            for (int b = 31; b >= 0; --b) {
                if ((int)__popcll(a1) + (int)__popcll(a2) == 1) break;
                unsigned long long on1 = __ballot(((id1 >> b) & 1u) != 0u);
                unsigned long long on2 = __ballot(((id2 >> b) & 1u) != 0u);
                unsigned long long z1 = a1 & ~on1;
                unsigned long long z2 = a2 & ~on2;
                int cz = (int)__popcll(z1) + (int)__popcll(z2);
                bool tz = (cz >= nd);
                a1 = tz ? z1 : (a1 & on1);
                a2 = tz ? z2 : (a2 & on2);
                nd = tz ? nd : (nd - cz);
            }
            if (a1) vidx = (unsigned)__builtin_amdgcn_readlane((int)id1, (int)__ffsll(a1) - 1);
            else    vidx = (unsigned)__builtin_amdgcn_readlane((int)id2, (int)__ffsll(a2) - 1);
        }

        bool sel1 = (lane < M)      && ((ud1 < v16) || ((ud1 == v16) && (all_ties || (id1 <= vidx))));
        bool sel2 = (lane + 64 < M) && ((ud2 < v16) || ((ud2 == v16) && (all_ties || (id2 <= vidx))));
        unsigned long long bs1 = __ballot(sel1);
        if (sel1) knn[qi*KNN + (int)__popcll(bs1 & ltm)] = (int)id1;
        const int c1 = (int)__popcll(bs1);
        unsigned long long bs2 = __ballot(sel2);
        if (sel2) knn[qi*KNN + c1 + (int)__popcll(bs2 & ltm)] = (int)id2;
    }
}

// ---------------- dispatch 3: final (dim-parallel, validated r11) ----------------

__device__ __forceinline__ float bflo(unsigned w) { return __uint_as_float(w << 16); }
__device__ __forceinline__ float bfhi(unsigned w) { return __uint_as_float(w & 0xFFFF0000u); }

template<int CTRL>
__device__ __forceinline__ float dppf(float v) {
    return __uint_as_float((unsigned)__builtin_amdgcn_update_dpp(
        0, (int)__float_as_uint(v), CTRL, 0xF, 0xF, true));
}

__global__ void __launch_bounds__(256) final_kernel(const __hip_bfloat16* __restrict__ Ub,
                                                    const __hip_bfloat16* __restrict__ Vb,
                                                    const int* __restrict__ knn,
                                                    const float* __restrict__ xyz,
                                                    const float* __restrict__ W2,
                                                    const float* __restrict__ b2,
                                                    float* __restrict__ out) {
    const int lane = threadIdx.x & 63;
    const int wv   = threadIdx.x >> 6;
    const int i    = blockIdx.x * 4 + wv;
    const int d0   = lane * 6;

    int jreg = knn[i*KNN + (lane & 15)];

    float u[6], w2l[6][3];
    {
        const unsigned* rowU = reinterpret_cast<const unsigned*>(Ub + (size_t)i * TD) + lane*3;
        unsigned a0 = rowU[0], a1 = rowU[1], a2 = rowU[2];
        u[0] = bflo(a0); u[1] = bfhi(a0);
        u[2] = bflo(a1); u[3] = bfhi(a1);
        u[4] = bflo(a2); u[5] = bfhi(a2);
    }
    #pragma unroll
    for (int t = 0; t < 6; ++t)
        #pragma unroll
        for (int c = 0; c < 3; ++c) w2l[t][c] = W2[(d0 + t)*3 + c];

    const unsigned* vbase = reinterpret_cast<const unsigned*>(Vb);
    const int voff = lane * 3;

    float pk0[16], pk1[16], pk2[16];
    unsigned va[2][4][3];

    #pragma unroll
    for (int t = 0; t < 4; ++t) {
        int j = __builtin_amdgcn_readlane(jreg, t);
        const unsigned* rv = vbase + (size_t)j * 192 + voff;
        va[0][t][0] = rv[0]; va[0][t][1] = rv[1]; va[0][t][2] = rv[2];
    }
    __builtin_amdgcn_sched_barrier(0);

    #pragma unroll
    for (int b = 0; b < 4; ++b) {
        if (b < 3) {
            #pragma unroll
            for (int t = 0; t < 4; ++t) {
                int j = __builtin_amdgcn_readlane(jreg, (b+1)*4 + t);
                const unsigned* rv = vbase + (size_t)j * 192 + voff;
                va[(b+1)&1][t][0] = rv[0];
                va[(b+1)&1][t][1] = rv[1];
                va[(b+1)&1][t][2] = rv[2];
            }
            __builtin_amdgcn_sched_barrier(0);
        }
        #pragma unroll
        for (int t = 0; t < 4; ++t) {
            const int kk = b*4 + t;
            unsigned a0 = va[b&1][t][0], a1 = va[b&1][t][1], a2 = va[b&1][t][2];
            float v0 = bflo(a0), v1 = bfhi(a0);
            float v2 = bflo(a1), v3 = bfhi(a1);
            float v4 = bflo(a2), v5 = bfhi(a2);
            float h0 = fmaxf(u[0] + v0, 0.f), h1 = fmaxf(u[1] + v1, 0.f);
            float h2 = fmaxf(u[2] + v2, 0.f), h3 = fmaxf(u[3] + v3, 0.f);
            float h4 = fmaxf(u[4] + v4, 0.f), h5 = fmaxf(u[5] + v5, 0.f);
            float s0 = 0.f, s1 = 0.f, s2 = 0.f;
            s0 = fmaf(h0, w2l[0][0], s0); s1 = fmaf(h0, w2l[0][1], s1); s2 = fmaf(h0, w2l[0][2], s2);
            s0 = fmaf(h1, w2l[1][0], s0); s1 = fmaf(h1, w2l[1][1], s1); s2 = fmaf(h1, w2l[1][2], s2);
            s0 = fmaf(h2, w2l[2][0], s0); s1 = fmaf(h2, w2l[2][1], s1); s2 = fmaf(h2, w2l[2][2], s2);
            s0 = fmaf(h3, w2l[3][0], s0); s1 = fmaf(h3, w2l[3][1], s1); s2 = fmaf(h3, w2l[3][2], s2);
            s0 = fmaf(h4, w2l[4][0], s0); s1 = fmaf(h4, w2l[4][1], s1); s2 = fmaf(h4, w2l[4][2], s2);
            s0 = fmaf(h5, w2l[5][0], s0); s1 = fmaf(h5, w2l[5][1], s1); s2 = fmaf(h5, w2l[5][2], s2);
            pk0[kk] = s0; pk1[kk] = s1; pk2[kk] = s2;
        }
    }

    #pragma unroll
    for (int kk = 0; kk < 16; ++kk) {
        float r0 = pk0[kk], r1 = pk1[kk], r2 = pk2[kk];
        r0 += dppf<0x121>(r0); r1 += dppf<0x121>(r1); r2 += dppf<0x121>(r2);
        r0 += dppf<0x122>(r0); r1 += dppf<0x122>(r1); r2 += dppf<0x122>(r2);
        r0 += dppf<0x124>(r0); r1 += dppf<0x124>(r1); r2 += dppf<0x124>(r2);
        r0 += dppf<0x128>(r0); r1 += dppf<0x128>(r1); r2 += dppf<0x128>(r2);
        r0 += __shfl_xor(r0, 16); r1 += __shfl_xor(r1, 16); r2 += __shfl_xor(r2, 16);
        r0 += __shfl_xor(r0, 32); r1 += __shfl_xor(r1, 32); r2 += __shfl_xor(r2, 32);
        pk0[kk] = r0; pk1[kk] = r1; pk2[kk] = r2;
    }
    float mx0 = pk0[0], mx1 = pk1[0], mx2 = pk2[0];
    #pragma unroll
    for (int kk = 1; kk < 16; ++kk) {
        mx0 = fmaxf(mx0, pk0[kk]);
        mx1 = fmaxf(mx1, pk1[kk]);
        mx2 = fmaxf(mx2, pk2[kk]);
    }

    if (lane == 0) {
        out[i*3+0] = xyz[i*3+0] + mx0 + b2[0];
        out[i*3+1] = xyz[i*3+1] + mx1 + b2[1];
        out[i*3+2] = xyz[i*3+2] + mx2 + b2[2];
    }
}

// ---------------- launch ----------------

extern "C" void kernel_launch(void* const* d_in, const int* in_sizes, int n_in,
                              void* d_out, int out_size, void* d_ws, size_t ws_size,
                              hipStream_t stream) {
    const float* xyz  = (const float*)d_in[0];
    const float* feat = (const float*)d_in[1];
    const float* W1   = (const float*)d_in[2];
    const float* b1   = (const float*)d_in[3];
    const float* W2   = (const float*)d_in[4];
    const float* b2   = (const float*)d_in[5];
    float* out = (float*)d_out;

    char* ws = (char*)d_ws;
    int*            knn   = (int*)(ws + 0);                   //   524288 B
    float*          stile = (float*)(ws + 524288);            //   163840 B
    __hip_bfloat16* Xb    = (__hip_bfloat16*)(ws + 688128);   //  6815744 B
    __hip_bfloat16* Wpt   = (__hip_bfloat16*)(ws + 7503872);  //   638976 B
    __hip_bfloat16* Ub    = (__hip_bfloat16*)(ws + 8142848);  //  6291456 B
    __hip_bfloat16* Vb    = (__hip_bfloat16*)(ws + 14434304); //  6291456 B
    int*            thi   = (int*)(ws + 20725760);            //      128 B
    int*            tlo   = (int*)(ws + 20725888);            //      128 B -> end 20726016

    prep_assign <<<dim3(NB_X + NB_W + NB_A), dim3(256), 0, stream>>>(
        feat, xyz, W1, Xb, Wpt, tlo, thi, stile);
    knn_gemm    <<<dim3(N + NGEMM_T),        dim3(64),  0, stream>>>(
        stile, tlo, thi, knn, Xb, Wpt, b1, Ub, Vb);
    final_kernel<<<dim3(N/4),                dim3(256), 0, stream>>>(
        Ub, Vb, knn, xyz, W2, b2, out);
}